// Round 4
// baseline (639.681 us; speedup 1.0000x reference)
//
#include <hip/hip_runtime.h>

// MoE: B=4,S=2048 -> T=8192 tokens, D=1024, H=2048, O=1024, E=8, K=2
#define T_TOKENS 8192
#define D_DIM 1024
#define H_DIM 2048
#define O_DIM 1024
#define E_NUM 8
#define NPAIR 16384   // T_TOKENS * 2

typedef unsigned short u16;
typedef __bf16 bf16x8 __attribute__((ext_vector_type(8)));
typedef float f32x4 __attribute__((ext_vector_type(4)));

__device__ inline u16 f2bf(float f) {
  union { float f; unsigned u; } v; v.f = f;
  unsigned r = v.u + 0x7FFFu + ((v.u >> 16) & 1u);   // RNE
  return (u16)(r >> 16);
}

// async 16B global -> LDS (deposits at wave-uniform base + lane*16)
__device__ __forceinline__ void gload16(const u16* g, u16* l) {
  __builtin_amdgcn_global_load_lds((const __attribute__((address_space(1))) void*)g,
                                   (__attribute__((address_space(3))) void*)l, 16, 0, 0);
}

// ---------------- prep: transpose+cast weights: [E,R,C] f32 -> [E,C,R] bf16 ----
__global__ void transpose_cvt_kernel(const float* __restrict__ w, u16* __restrict__ wt,
                                     int R, int C) {
  __shared__ float tile[32][33];
  int e = blockIdx.z;
  int c0 = blockIdx.x * 32, r0 = blockIdx.y * 32;
  const float* wp = w + (size_t)e * R * C;
  u16* wtp = wt + (size_t)e * R * C;
  int tx = threadIdx.x, ty = threadIdx.y;  // (32,8)
  #pragma unroll
  for (int j = 0; j < 32; j += 8)
    tile[ty + j][tx] = wp[(size_t)(r0 + ty + j) * C + c0 + tx];
  __syncthreads();
  #pragma unroll
  for (int j = 0; j < 32; j += 8)
    wtp[(size_t)(c0 + ty + j) * R + r0 + tx] = f2bf(tile[tx][ty + j]);
}

// ---------------- gating + x->bf16 cast fused (NO atomics) ----------------
__global__ void gate_kernel(const float* __restrict__ x, const float* __restrict__ gw,
                            const float* __restrict__ gb, int* __restrict__ topk_idx,
                            float* __restrict__ topk_val, u16* __restrict__ xb) {
  int t = blockIdx.x * 4 + (threadIdx.x >> 6);   // one wave per token
  int lane = threadIdx.x & 63;
  const float4* xr4 = (const float4*)(x + (size_t)t * D_DIM);
  const float4* gw4 = (const float4*)gw;
  u16* xbr = xb + (size_t)t * D_DIM;
  float acc[E_NUM];
  #pragma unroll
  for (int e = 0; e < E_NUM; e++) acc[e] = 0.f;
  #pragma unroll
  for (int it = 0; it < D_DIM / 256; ++it) {
    float4 xv = xr4[it * 64 + lane];
    ushort4 o;
    o.x = f2bf(xv.x); o.y = f2bf(xv.y); o.z = f2bf(xv.z); o.w = f2bf(xv.w);
    *(ushort4*)(xbr + (it * 64 + lane) * 4) = o;
    #pragma unroll
    for (int e = 0; e < E_NUM; e++) {
      float4 wv = gw4[e * (D_DIM / 4) + it * 64 + lane];
      acc[e] += xv.x * wv.x + xv.y * wv.y + xv.z * wv.z + xv.w * wv.w;
    }
  }
  #pragma unroll
  for (int e = 0; e < E_NUM; e++) {
    #pragma unroll
    for (int o = 32; o > 0; o >>= 1) acc[e] += __shfl_down(acc[e], o);
  }
  if (lane == 0) {
    float l[E_NUM], mx = -1e30f;
    #pragma unroll
    for (int e = 0; e < E_NUM; e++) { l[e] = acc[e] + gb[e]; mx = fmaxf(mx, l[e]); }
    float p[E_NUM], s = 0.f;
    #pragma unroll
    for (int e = 0; e < E_NUM; e++) { p[e] = expf(l[e] - mx); s += p[e]; }
    float inv = 1.f / s;
    int i1 = 0;
    #pragma unroll
    for (int e = 1; e < E_NUM; e++) if (p[e] > p[i1]) i1 = e;   // strict >: lowest idx on tie
    int i2 = (i1 == 0) ? 1 : 0;
    #pragma unroll
    for (int e = 0; e < E_NUM; e++) if (e != i1 && e != i2 && p[e] > p[i2]) i2 = e;
    topk_idx[t * 2] = i1;     topk_idx[t * 2 + 1] = i2;
    topk_val[t * 2] = p[i1] * inv; topk_val[t * 2 + 1] = p[i2] * inv;
  }
}

// ---------------- histogram + scan: 1 block, ballot-aggregated, no global atomics ----
__global__ void histscan_kernel(const int* __restrict__ topk_idx,
                                int* __restrict__ counts, int* __restrict__ eoff) {
  __shared__ int wh[4][E_NUM];
  int tid = threadIdx.x;           // 256 threads
  int lane = tid & 63, wave = tid >> 6;
  int myc = 0;                     // lane e (<8) accumulates count of expert e
  for (int i = tid; i < NPAIR; i += 256) {
    int e = topk_idx[i];
    #pragma unroll
    for (int ee = 0; ee < E_NUM; ee++) {
      unsigned long long m = __ballot(e == ee);
      if (lane == ee) myc += __popcll(m);
    }
  }
  if (lane < E_NUM) wh[wave][lane] = myc;
  __syncthreads();
  if (tid == 0) {
    int s = 0;
    for (int e = 0; e < E_NUM; e++) {
      int c = wh[0][e] + wh[1][e] + wh[2][e] + wh[3][e];
      counts[e] = c;
      eoff[e] = s;
      s += c;
    }
    eoff[E_NUM] = s;
  }
}

// ---------------- scatter: per-block LDS agg + padded global cursors ----------------
__global__ void scatter_kernel(const int* __restrict__ topk_idx, const float* __restrict__ topk_val,
                               const int* __restrict__ eoff, int* __restrict__ cursor_pad,
                               int* __restrict__ pair_token, float* __restrict__ pair_gate) {
  __shared__ int lhist[E_NUM];
  __shared__ int lbase[E_NUM];
  int tid = threadIdx.x;
  int t = blockIdx.x * 256 + tid;
  if (tid < E_NUM) lhist[tid] = 0;
  __syncthreads();
  int e0 = topk_idx[t * 2], e1 = topk_idx[t * 2 + 1];
  int r0 = atomicAdd(&lhist[e0], 1);
  int r1 = atomicAdd(&lhist[e1], 1);
  __syncthreads();
  if (tid < E_NUM) lbase[tid] = eoff[tid] + atomicAdd(&cursor_pad[tid * 32], lhist[tid]);
  __syncthreads();
  int p0 = lbase[e0] + r0;
  int p1 = lbase[e1] + r1;
  pair_token[p0] = t; pair_gate[p0] = topk_val[t * 2];
  pair_token[p1] = t; pair_gate[p1] = topk_val[t * 2 + 1];
}

// LDS swizzle: logical (row, g) stored at slot row*4 + (g ^ ((row>>1)&3)),
// 16B slots, row stride 64B -> ds_read_b128 is 2-way (free, m136).
// K-loop: double-buffered LDS; DMA for tile k+1 issued AFTER the barrier so it
// stays in flight through tile k's MFMA phase (one barrier per iteration).

// ---------------- GEMM1: h = relu(x[tok] @ w1[e] + b1[e]) -> hbuf bf16 ----------------
__global__ __launch_bounds__(256, 4) void gemm1_kernel(
    const u16* __restrict__ xb, const u16* __restrict__ w1t, const float* __restrict__ b1,
    const int* __restrict__ pair_token, const int* __restrict__ eoff,
    const int* __restrict__ ecnt, u16* __restrict__ hbuf) {
  const int e = blockIdx.z;
  const int ne = ecnt[e];
  const int m0t = blockIdx.x * 128;          // m fastest: XCDs share one B panel
  if (m0t >= ne) return;
  const int off = eoff[e];
  const int n0 = blockIdx.y * 128;

  __shared__ __align__(16) u16 As[2 * 128 * 32];
  __shared__ __align__(16) u16 Bs[2 * 128 * 32];

  const int tid = threadIdx.x;
  const int wid = tid >> 6;
  const int lane = tid & 63;

  // staging geometry: wave wid covers rows [wid*32, wid*32+32) in two issues
  const int strow = lane >> 2;                         // 0..15 within issue
  const int gsw = (lane & 3) ^ ((lane >> 3) & 3);      // swizzled logical group
  const int r0 = wid * 32 + strow;
  const int r1 = r0 + 16;
  int gm0 = m0t + r0, gm1 = m0t + r1;
  int tok0 = (gm0 < ne) ? pair_token[off + gm0] : 0;
  int tok1 = (gm1 < ne) ? pair_token[off + gm1] : 0;
  const u16* a0 = xb + (size_t)tok0 * D_DIM + gsw * 8;
  const u16* a1 = xb + (size_t)tok1 * D_DIM + gsw * 8;
  const u16* bp0 = w1t + ((size_t)e * H_DIM + (n0 + r0)) * D_DIM + gsw * 8;
  const u16* bp1 = w1t + ((size_t)e * H_DIM + (n0 + r1)) * D_DIM + gsw * 8;
  const int dep = wid * 1024;                          // u16 units within a buffer

  const int wm = (wid & 1) * 64;
  const int wn = (wid >> 1) * 64;
  const int lrow = lane & 15;
  const int quad = lane >> 4;
  const int gq = quad ^ ((lrow >> 1) & 3);             // swizzled read group

  f32x4 acc[4][4] = {};

  // preload tile 0 into buffer 0
  gload16(a0, As + dep);       gload16(a1, As + dep + 512);
  gload16(bp0, Bs + dep);      gload16(bp1, Bs + dep + 512);

  int p = 0;
  for (int k0 = 0; k0 < D_DIM; k0 += 32) {
    __syncthreads();                                   // drains DMA for buffer p
    int kn = k0 + 32;
    if (kn < D_DIM) {                                  // uniform branch
      int qb = (p ^ 1) * 4096;
      gload16(a0 + kn, As + qb + dep);   gload16(a1 + kn, As + qb + dep + 512);
      gload16(bp0 + kn, Bs + qb + dep);  gload16(bp1 + kn, Bs + qb + dep + 512);
    }
    const int base = p * 4096;
    bf16x8 af[4], bfr[4];
    #pragma unroll
    for (int i = 0; i < 4; i++) af[i] = *(const bf16x8*)&As[base + (wm + i * 16 + lrow) * 32 + gq * 8];
    #pragma unroll
    for (int j = 0; j < 4; j++) bfr[j] = *(const bf16x8*)&Bs[base + (wn + j * 16 + lrow) * 32 + gq * 8];
    #pragma unroll
    for (int i = 0; i < 4; i++)
      #pragma unroll
      for (int j = 0; j < 4; j++)
        acc[i][j] = __builtin_amdgcn_mfma_f32_16x16x32_bf16(af[i], bfr[j], acc[i][j], 0, 0, 0);
    p ^= 1;
  }
  // epilogue: +b1, relu, bf16 store. C/D: col=lane&15, row=quad*4+reg
  #pragma unroll
  for (int i = 0; i < 4; i++) {
    #pragma unroll
    for (int r = 0; r < 4; r++) {
      int m = wm + i * 16 + quad * 4 + r;
      int gm = m0t + m;
      if (gm >= ne) continue;
      size_t rowbase = (size_t)(off + gm) * H_DIM;
      #pragma unroll
      for (int j = 0; j < 4; j++) {
        int n = n0 + wn + j * 16 + lrow;
        float v = acc[i][j][r] + b1[e * H_DIM + n];
        v = v > 0.f ? v : 0.f;
        hbuf[rowbase + n] = f2bf(v);
      }
    }
  }
}

// ---------------- GEMM2: out[tok] += gate * (h @ w2[e] + b2[e]) ----------------
__global__ __launch_bounds__(256, 4) void gemm2_kernel(
    const u16* __restrict__ hbuf, const u16* __restrict__ w2t, const float* __restrict__ b2,
    const int* __restrict__ pair_token, const float* __restrict__ pair_gate,
    const int* __restrict__ eoff, const int* __restrict__ ecnt, float* __restrict__ out) {
  const int e = blockIdx.z;
  const int ne = ecnt[e];
  const int m0t = blockIdx.x * 128;
  if (m0t >= ne) return;
  const int off = eoff[e];
  const int n0 = blockIdx.y * 128;

  __shared__ __align__(16) u16 As[2 * 128 * 32];
  __shared__ __align__(16) u16 Bs[2 * 128 * 32];

  const int tid = threadIdx.x;
  const int wid = tid >> 6;
  const int lane = tid & 63;

  const int strow = lane >> 2;
  const int gsw = (lane & 3) ^ ((lane >> 3) & 3);
  const int r0 = wid * 32 + strow;
  const int r1 = r0 + 16;
  // hbuf has 128 slack rows past NPAIR; values beyond ne are discarded in epilogue
  const u16* a0 = hbuf + (size_t)(off + m0t + r0) * H_DIM + gsw * 8;
  const u16* a1 = hbuf + (size_t)(off + m0t + r1) * H_DIM + gsw * 8;
  const u16* bp0 = w2t + ((size_t)e * O_DIM + (n0 + r0)) * H_DIM + gsw * 8;
  const u16* bp1 = w2t + ((size_t)e * O_DIM + (n0 + r1)) * H_DIM + gsw * 8;
  const int dep = wid * 1024;

  const int wm = (wid & 1) * 64;
  const int wn = (wid >> 1) * 64;
  const int lrow = lane & 15;
  const int quad = lane >> 4;
  const int gq = quad ^ ((lrow >> 1) & 3);

  f32x4 acc[4][4] = {};

  gload16(a0, As + dep);       gload16(a1, As + dep + 512);
  gload16(bp0, Bs + dep);      gload16(bp1, Bs + dep + 512);

  int p = 0;
  for (int k0 = 0; k0 < H_DIM; k0 += 32) {
    __syncthreads();
    int kn = k0 + 32;
    if (kn < H_DIM) {
      int qb = (p ^ 1) * 4096;
      gload16(a0 + kn, As + qb + dep);   gload16(a1 + kn, As + qb + dep + 512);
      gload16(bp0 + kn, Bs + qb + dep);  gload16(bp1 + kn, Bs + qb + dep + 512);
    }
    const int base = p * 4096;
    bf16x8 af[4], bfr[4];
    #pragma unroll
    for (int i = 0; i < 4; i++) af[i] = *(const bf16x8*)&As[base + (wm + i * 16 + lrow) * 32 + gq * 8];
    #pragma unroll
    for (int j = 0; j < 4; j++) bfr[j] = *(const bf16x8*)&Bs[base + (wn + j * 16 + lrow) * 32 + gq * 8];
    #pragma unroll
    for (int i = 0; i < 4; i++)
      #pragma unroll
      for (int j = 0; j < 4; j++)
        acc[i][j] = __builtin_amdgcn_mfma_f32_16x16x32_bf16(af[i], bfr[j], acc[i][j], 0, 0, 0);
    p ^= 1;
  }
  #pragma unroll
  for (int i = 0; i < 4; i++) {
    #pragma unroll
    for (int r = 0; r < 4; r++) {
      int m = wm + i * 16 + quad * 4 + r;
      int gm = m0t + m;
      if (gm >= ne) continue;
      int pair = off + gm;
      int tok = pair_token[pair];
      float g = pair_gate[pair];
      #pragma unroll
      for (int j = 0; j < 4; j++) {
        int n = n0 + wn + j * 16 + lrow;
        float v = (acc[i][j][r] + b2[e * O_DIM + n]) * g;
        atomicAdd(&out[(size_t)tok * O_DIM + n], v);
      }
    }
  }
}

extern "C" void kernel_launch(void* const* d_in, const int* in_sizes, int n_in,
                              void* d_out, int out_size, void* d_ws, size_t ws_size,
                              hipStream_t stream) {
  const float* x  = (const float*)d_in[0];
  const float* gw = (const float*)d_in[1];
  const float* gb = (const float*)d_in[2];
  const float* w1 = (const float*)d_in[3];
  const float* b1 = (const float*)d_in[4];
  const float* w2 = (const float*)d_in[5];
  const float* b2 = (const float*)d_in[6];
  float* out = (float*)d_out;

  char* ws = (char*)d_ws;
  size_t off = 0;
  auto take = [&](size_t bytes) -> char* {
    char* p = ws + off;
    off = (off + bytes + 255) & ~(size_t)255;
    return p;
  };
  int*   meta       = (int*)take(2048);                          // cursor_pad[8*32] | counts[8] | eoff[9]
  int*   cursor_pad = meta;
  int*   counts     = meta + 256;
  int*   eoff       = meta + 264;
  int*   topk_idx   = (int*)take((size_t)T_TOKENS * 2 * 4);
  float* topk_val   = (float*)take((size_t)T_TOKENS * 2 * 4);
  int*   pair_token = (int*)take((size_t)(NPAIR + 256) * 4);
  float* pair_gate  = (float*)take((size_t)(NPAIR + 256) * 4);
  u16*   xb         = (u16*)take((size_t)T_TOKENS * D_DIM * 2);
  u16*   w1t        = (u16*)take((size_t)E_NUM * D_DIM * H_DIM * 2);
  u16*   w2t        = (u16*)take((size_t)E_NUM * H_DIM * O_DIM * 2);
  u16*   hbuf       = (u16*)take((size_t)(NPAIR + 128) * H_DIM * 2);

  hipMemsetAsync(meta, 0, 2048, stream);
  hipMemsetAsync(out, 0, (size_t)T_TOKENS * O_DIM * 4, stream);

  transpose_cvt_kernel<<<dim3(H_DIM / 32, D_DIM / 32, E_NUM), dim3(32, 8), 0, stream>>>(w1, w1t, D_DIM, H_DIM);
  transpose_cvt_kernel<<<dim3(O_DIM / 32, H_DIM / 32, E_NUM), dim3(32, 8), 0, stream>>>(w2, w2t, H_DIM, O_DIM);
  gate_kernel<<<T_TOKENS / 4, 256, 0, stream>>>(x, gw, gb, topk_idx, topk_val, xb);
  histscan_kernel<<<1, 256, 0, stream>>>(topk_idx, counts, eoff);
  scatter_kernel<<<T_TOKENS / 256, 256, 0, stream>>>(topk_idx, topk_val, eoff, cursor_pad, pair_token, pair_gate);
  gemm1_kernel<<<dim3(NPAIR / 128, H_DIM / 128, E_NUM), 256, 0, stream>>>(xb, w1t, b1, pair_token, eoff, counts, hbuf);
  gemm2_kernel<<<dim3(NPAIR / 128, O_DIM / 128, E_NUM), 256, 0, stream>>>(hbuf, w2t, b2, pair_token, pair_gate, eoff, counts, out);
}

// Round 5
// 493.939 us; speedup vs baseline: 1.2951x; 1.2951x over previous
//
#include <hip/hip_runtime.h>

// MoE: B=4,S=2048 -> T=8192 tokens, D=1024, H=2048, O=1024, E=8, K=2
#define T_TOKENS 8192
#define D_DIM 1024
#define H_DIM 2048
#define O_DIM 1024
#define E_NUM 8
#define NPAIR 16384   // T_TOKENS * 2

typedef unsigned short u16;
typedef __bf16 bf16x8 __attribute__((ext_vector_type(8)));
typedef float f32x4 __attribute__((ext_vector_type(4)));

__device__ inline u16 f2bf(float f) {
  union { float f; unsigned u; } v; v.f = f;
  unsigned r = v.u + 0x7FFFu + ((v.u >> 16) & 1u);   // RNE
  return (u16)(r >> 16);
}

// async 16B global -> LDS (deposits at wave-uniform base + lane*16)
__device__ __forceinline__ void gload16(const u16* g, u16* l) {
  __builtin_amdgcn_global_load_lds((const __attribute__((address_space(1))) void*)g,
                                   (__attribute__((address_space(3))) void*)l, 16, 0, 0);
}

// ---------------- prep: transpose+cast weights: [E,R,C] f32 -> [E,C,R] bf16 ----
__global__ void transpose_cvt_kernel(const float* __restrict__ w, u16* __restrict__ wt,
                                     int R, int C) {
  __shared__ float tile[32][33];
  int e = blockIdx.z;
  int c0 = blockIdx.x * 32, r0 = blockIdx.y * 32;
  const float* wp = w + (size_t)e * R * C;
  u16* wtp = wt + (size_t)e * R * C;
  int tx = threadIdx.x, ty = threadIdx.y;  // (32,8)
  #pragma unroll
  for (int j = 0; j < 32; j += 8)
    tile[ty + j][tx] = wp[(size_t)(r0 + ty + j) * C + c0 + tx];
  __syncthreads();
  #pragma unroll
  for (int j = 0; j < 32; j += 8)
    wtp[(size_t)(c0 + ty + j) * R + r0 + tx] = f2bf(tile[tx][ty + j]);
}

// ---------------- gating + x->bf16 cast fused (NO atomics) ----------------
__global__ void gate_kernel(const float* __restrict__ x, const float* __restrict__ gw,
                            const float* __restrict__ gb, int* __restrict__ topk_idx,
                            float* __restrict__ topk_val, u16* __restrict__ xb) {
  int t = blockIdx.x * 4 + (threadIdx.x >> 6);   // one wave per token
  int lane = threadIdx.x & 63;
  const float4* xr4 = (const float4*)(x + (size_t)t * D_DIM);
  const float4* gw4 = (const float4*)gw;
  u16* xbr = xb + (size_t)t * D_DIM;
  float acc[E_NUM];
  #pragma unroll
  for (int e = 0; e < E_NUM; e++) acc[e] = 0.f;
  #pragma unroll
  for (int it = 0; it < D_DIM / 256; ++it) {
    float4 xv = xr4[it * 64 + lane];
    ushort4 o;
    o.x = f2bf(xv.x); o.y = f2bf(xv.y); o.z = f2bf(xv.z); o.w = f2bf(xv.w);
    *(ushort4*)(xbr + (it * 64 + lane) * 4) = o;
    #pragma unroll
    for (int e = 0; e < E_NUM; e++) {
      float4 wv = gw4[e * (D_DIM / 4) + it * 64 + lane];
      acc[e] += xv.x * wv.x + xv.y * wv.y + xv.z * wv.z + xv.w * wv.w;
    }
  }
  #pragma unroll
  for (int e = 0; e < E_NUM; e++) {
    #pragma unroll
    for (int o = 32; o > 0; o >>= 1) acc[e] += __shfl_down(acc[e], o);
  }
  if (lane == 0) {
    float l[E_NUM], mx = -1e30f;
    #pragma unroll
    for (int e = 0; e < E_NUM; e++) { l[e] = acc[e] + gb[e]; mx = fmaxf(mx, l[e]); }
    float p[E_NUM], s = 0.f;
    #pragma unroll
    for (int e = 0; e < E_NUM; e++) { p[e] = expf(l[e] - mx); s += p[e]; }
    float inv = 1.f / s;
    int i1 = 0;
    #pragma unroll
    for (int e = 1; e < E_NUM; e++) if (p[e] > p[i1]) i1 = e;   // strict >: lowest idx on tie
    int i2 = (i1 == 0) ? 1 : 0;
    #pragma unroll
    for (int e = 0; e < E_NUM; e++) if (e != i1 && e != i2 && p[e] > p[i2]) i2 = e;
    topk_idx[t * 2] = i1;     topk_idx[t * 2 + 1] = i2;
    topk_val[t * 2] = p[i1] * inv; topk_val[t * 2 + 1] = p[i2] * inv;
  }
}

// ---------------- histogram + scan: 1 block, ballot-aggregated, no global atomics ----
__global__ void histscan_kernel(const int* __restrict__ topk_idx,
                                int* __restrict__ counts, int* __restrict__ eoff) {
  __shared__ int wh[4][E_NUM];
  int tid = threadIdx.x;           // 256 threads
  int lane = tid & 63, wave = tid >> 6;
  int myc = 0;                     // lane e (<8) accumulates count of expert e
  for (int i = tid; i < NPAIR; i += 256) {
    int e = topk_idx[i];
    #pragma unroll
    for (int ee = 0; ee < E_NUM; ee++) {
      unsigned long long m = __ballot(e == ee);
      if (lane == ee) myc += __popcll(m);
    }
  }
  if (lane < E_NUM) wh[wave][lane] = myc;
  __syncthreads();
  if (tid == 0) {
    int s = 0;
    for (int e = 0; e < E_NUM; e++) {
      int c = wh[0][e] + wh[1][e] + wh[2][e] + wh[3][e];
      counts[e] = c;
      eoff[e] = s;
      s += c;
    }
    eoff[E_NUM] = s;
  }
}

// ---------------- scatter: per-block LDS agg + padded global cursors ----------------
__global__ void scatter_kernel(const int* __restrict__ topk_idx, const float* __restrict__ topk_val,
                               const int* __restrict__ eoff, int* __restrict__ cursor_pad,
                               int* __restrict__ pair_token, float* __restrict__ pair_gate) {
  __shared__ int lhist[E_NUM];
  __shared__ int lbase[E_NUM];
  int tid = threadIdx.x;
  int t = blockIdx.x * 256 + tid;
  if (tid < E_NUM) lhist[tid] = 0;
  __syncthreads();
  int e0 = topk_idx[t * 2], e1 = topk_idx[t * 2 + 1];
  int r0 = atomicAdd(&lhist[e0], 1);
  int r1 = atomicAdd(&lhist[e1], 1);
  __syncthreads();
  if (tid < E_NUM) lbase[tid] = eoff[tid] + atomicAdd(&cursor_pad[tid * 32], lhist[tid]);
  __syncthreads();
  int p0 = lbase[e0] + r0;
  int p1 = lbase[e1] + r1;
  pair_token[p0] = t; pair_gate[p0] = topk_val[t * 2];
  pair_token[p1] = t; pair_gate[p1] = topk_val[t * 2 + 1];
}

// BK=64 single-buffer GEMM. LDS layout: row stride 64 u16 (128B); 16B chunk
// g of row r stored at slot (g ^ (r&7)) -> ds_read_b128 hits the 8-access/bank
// minimum (0 counted conflicts) and global_load_lds's lane-contiguous deposit
// maps cleanly (deposit slot = lane&7, row = base + lane>>3).
// 2 barriers per 64-K tile: half the drain count of the BK=32 structure.

// ---------------- GEMM1: h = relu(x[tok] @ w1[e] + b1[e]) -> hbuf bf16 ----------------
__global__ __launch_bounds__(256, 3) void gemm1_kernel(
    const u16* __restrict__ xb, const u16* __restrict__ w1t, const float* __restrict__ b1,
    const int* __restrict__ pair_token, const int* __restrict__ eoff,
    const int* __restrict__ ecnt, u16* __restrict__ hbuf) {
  const int e = blockIdx.z;
  const int ne = ecnt[e];
  const int m0t = blockIdx.y * 128;
  if (m0t >= ne) return;
  const int off = eoff[e];
  const int n0 = blockIdx.x * 128;

  __shared__ __align__(16) u16 As[128 * 64];
  __shared__ __align__(16) u16 Bs[128 * 64];

  const int tid = threadIdx.x;
  const int wid = tid >> 6;
  const int lane = tid & 63;

  // staging: wave wid covers rows [wid*32, wid*32+32), 4 issues of 8 rows
  const int strow8 = lane >> 3;          // 0..7
  const int slot = lane & 7;             // physical 16B slot within row
  const u16* aptr[4]; const u16* bptr[4];
  u16* lA[4]; u16* lB[4];
  #pragma unroll
  for (int j = 0; j < 4; j++) {
    int r = wid * 32 + j * 8 + strow8;
    int gm = m0t + r;
    int tok = (gm < ne) ? pair_token[off + gm] : 0;
    int gl = slot ^ (r & 7);             // logical chunk this lane fetches
    aptr[j] = xb + (size_t)tok * D_DIM + gl * 8;
    bptr[j] = w1t + ((size_t)e * H_DIM + (n0 + r)) * D_DIM + gl * 8;
    lA[j] = As + wid * 2048 + j * 512;
    lB[j] = Bs + wid * 2048 + j * 512;
  }

  const int wm = (wid & 1) * 64;
  const int wn = (wid >> 1) * 64;
  const int lrow = lane & 15;
  const int quad = lane >> 4;
  const int pg0 = quad ^ (lrow & 7);            // k-half 0 physical slot
  const int pg1 = (quad + 4) ^ (lrow & 7);      // k-half 1 physical slot

  f32x4 acc[4][4] = {};

  for (int k0 = 0; k0 < D_DIM; k0 += 64) {
    #pragma unroll
    for (int j = 0; j < 4; j++) { gload16(aptr[j] + k0, lA[j]); gload16(bptr[j] + k0, lB[j]); }
    __syncthreads();
    {
      bf16x8 af[4], bfr[4];
      #pragma unroll
      for (int i = 0; i < 4; i++) af[i] = *(const bf16x8*)&As[(wm + i * 16 + lrow) * 64 + pg0 * 8];
      #pragma unroll
      for (int j = 0; j < 4; j++) bfr[j] = *(const bf16x8*)&Bs[(wn + j * 16 + lrow) * 64 + pg0 * 8];
      #pragma unroll
      for (int i = 0; i < 4; i++)
        #pragma unroll
        for (int j = 0; j < 4; j++)
          acc[i][j] = __builtin_amdgcn_mfma_f32_16x16x32_bf16(af[i], bfr[j], acc[i][j], 0, 0, 0);
    }
    {
      bf16x8 af[4], bfr[4];
      #pragma unroll
      for (int i = 0; i < 4; i++) af[i] = *(const bf16x8*)&As[(wm + i * 16 + lrow) * 64 + pg1 * 8];
      #pragma unroll
      for (int j = 0; j < 4; j++) bfr[j] = *(const bf16x8*)&Bs[(wn + j * 16 + lrow) * 64 + pg1 * 8];
      #pragma unroll
      for (int i = 0; i < 4; i++)
        #pragma unroll
        for (int j = 0; j < 4; j++)
          acc[i][j] = __builtin_amdgcn_mfma_f32_16x16x32_bf16(af[i], bfr[j], acc[i][j], 0, 0, 0);
    }
    __syncthreads();
  }
  // epilogue: +b1, relu, bf16 store. C/D: col=lane&15, row=quad*4+reg
  #pragma unroll
  for (int i = 0; i < 4; i++) {
    #pragma unroll
    for (int r = 0; r < 4; r++) {
      int m = wm + i * 16 + quad * 4 + r;
      int gm = m0t + m;
      if (gm >= ne) continue;
      size_t rowbase = (size_t)(off + gm) * H_DIM;
      #pragma unroll
      for (int j = 0; j < 4; j++) {
        int n = n0 + wn + j * 16 + lrow;
        float v = acc[i][j][r] + b1[e * H_DIM + n];
        v = v > 0.f ? v : 0.f;
        hbuf[rowbase + n] = f2bf(v);
      }
    }
  }
}

// ---------------- GEMM2: out[tok] += gate * (h @ w2[e] + b2[e]) ----------------
__global__ __launch_bounds__(256, 3) void gemm2_kernel(
    const u16* __restrict__ hbuf, const u16* __restrict__ w2t, const float* __restrict__ b2,
    const int* __restrict__ pair_token, const float* __restrict__ pair_gate,
    const int* __restrict__ eoff, const int* __restrict__ ecnt, float* __restrict__ out) {
  const int e = blockIdx.z;
  const int ne = ecnt[e];
  const int m0t = blockIdx.y * 128;
  if (m0t >= ne) return;
  const int off = eoff[e];
  const int n0 = blockIdx.x * 128;

  __shared__ __align__(16) u16 As[128 * 64];
  __shared__ __align__(16) u16 Bs[128 * 64];

  const int tid = threadIdx.x;
  const int wid = tid >> 6;
  const int lane = tid & 63;

  const int strow8 = lane >> 3;
  const int slot = lane & 7;
  const u16* aptr[4]; const u16* bptr[4];
  u16* lA[4]; u16* lB[4];
  #pragma unroll
  for (int j = 0; j < 4; j++) {
    int r = wid * 32 + j * 8 + strow8;
    int gl = slot ^ (r & 7);
    // hbuf has 128 slack rows past NPAIR; out-of-range rows discarded in epilogue
    aptr[j] = hbuf + (size_t)(off + m0t + r) * H_DIM + gl * 8;
    bptr[j] = w2t + ((size_t)e * O_DIM + (n0 + r)) * H_DIM + gl * 8;
    lA[j] = As + wid * 2048 + j * 512;
    lB[j] = Bs + wid * 2048 + j * 512;
  }

  const int wm = (wid & 1) * 64;
  const int wn = (wid >> 1) * 64;
  const int lrow = lane & 15;
  const int quad = lane >> 4;
  const int pg0 = quad ^ (lrow & 7);
  const int pg1 = (quad + 4) ^ (lrow & 7);

  f32x4 acc[4][4] = {};

  for (int k0 = 0; k0 < H_DIM; k0 += 64) {
    #pragma unroll
    for (int j = 0; j < 4; j++) { gload16(aptr[j] + k0, lA[j]); gload16(bptr[j] + k0, lB[j]); }
    __syncthreads();
    {
      bf16x8 af[4], bfr[4];
      #pragma unroll
      for (int i = 0; i < 4; i++) af[i] = *(const bf16x8*)&As[(wm + i * 16 + lrow) * 64 + pg0 * 8];
      #pragma unroll
      for (int j = 0; j < 4; j++) bfr[j] = *(const bf16x8*)&Bs[(wn + j * 16 + lrow) * 64 + pg0 * 8];
      #pragma unroll
      for (int i = 0; i < 4; i++)
        #pragma unroll
        for (int j = 0; j < 4; j++)
          acc[i][j] = __builtin_amdgcn_mfma_f32_16x16x32_bf16(af[i], bfr[j], acc[i][j], 0, 0, 0);
    }
    {
      bf16x8 af[4], bfr[4];
      #pragma unroll
      for (int i = 0; i < 4; i++) af[i] = *(const bf16x8*)&As[(wm + i * 16 + lrow) * 64 + pg1 * 8];
      #pragma unroll
      for (int j = 0; j < 4; j++) bfr[j] = *(const bf16x8*)&Bs[(wn + j * 16 + lrow) * 64 + pg1 * 8];
      #pragma unroll
      for (int i = 0; i < 4; i++)
        #pragma unroll
        for (int j = 0; j < 4; j++)
          acc[i][j] = __builtin_amdgcn_mfma_f32_16x16x32_bf16(af[i], bfr[j], acc[i][j], 0, 0, 0);
    }
    __syncthreads();
  }
  #pragma unroll
  for (int i = 0; i < 4; i++) {
    #pragma unroll
    for (int r = 0; r < 4; r++) {
      int m = wm + i * 16 + quad * 4 + r;
      int gm = m0t + m;
      if (gm >= ne) continue;
      int pair = off + gm;
      int tok = pair_token[pair];
      float g = pair_gate[pair];
      #pragma unroll
      for (int j = 0; j < 4; j++) {
        int n = n0 + wn + j * 16 + lrow;
        float v = (acc[i][j][r] + b2[e * O_DIM + n]) * g;
        atomicAdd(&out[(size_t)tok * O_DIM + n], v);
      }
    }
  }
}

extern "C" void kernel_launch(void* const* d_in, const int* in_sizes, int n_in,
                              void* d_out, int out_size, void* d_ws, size_t ws_size,
                              hipStream_t stream) {
  const float* x  = (const float*)d_in[0];
  const float* gw = (const float*)d_in[1];
  const float* gb = (const float*)d_in[2];
  const float* w1 = (const float*)d_in[3];
  const float* b1 = (const float*)d_in[4];
  const float* w2 = (const float*)d_in[5];
  const float* b2 = (const float*)d_in[6];
  float* out = (float*)d_out;

  char* ws = (char*)d_ws;
  size_t off = 0;
  auto take = [&](size_t bytes) -> char* {
    char* p = ws + off;
    off = (off + bytes + 255) & ~(size_t)255;
    return p;
  };
  int*   meta       = (int*)take(2048);                          // cursor_pad[8*32] | counts[8] | eoff[9]
  int*   cursor_pad = meta;
  int*   counts     = meta + 256;
  int*   eoff       = meta + 264;
  int*   topk_idx   = (int*)take((size_t)T_TOKENS * 2 * 4);
  float* topk_val   = (float*)take((size_t)T_TOKENS * 2 * 4);
  int*   pair_token = (int*)take((size_t)(NPAIR + 256) * 4);
  float* pair_gate  = (float*)take((size_t)(NPAIR + 256) * 4);
  u16*   xb         = (u16*)take((size_t)T_TOKENS * D_DIM * 2);
  u16*   w1t        = (u16*)take((size_t)E_NUM * D_DIM * H_DIM * 2);
  u16*   w2t        = (u16*)take((size_t)E_NUM * H_DIM * O_DIM * 2);
  u16*   hbuf       = (u16*)take((size_t)(NPAIR + 128) * H_DIM * 2);

  hipMemsetAsync(meta, 0, 2048, stream);
  hipMemsetAsync(out, 0, (size_t)T_TOKENS * O_DIM * 4, stream);

  transpose_cvt_kernel<<<dim3(H_DIM / 32, D_DIM / 32, E_NUM), dim3(32, 8), 0, stream>>>(w1, w1t, D_DIM, H_DIM);
  transpose_cvt_kernel<<<dim3(O_DIM / 32, H_DIM / 32, E_NUM), dim3(32, 8), 0, stream>>>(w2, w2t, H_DIM, O_DIM);
  gate_kernel<<<T_TOKENS / 4, 256, 0, stream>>>(x, gw, gb, topk_idx, topk_val, xb);
  histscan_kernel<<<1, 256, 0, stream>>>(topk_idx, counts, eoff);
  scatter_kernel<<<T_TOKENS / 256, 256, 0, stream>>>(topk_idx, topk_val, eoff, cursor_pad, pair_token, pair_gate);
  gemm1_kernel<<<dim3(H_DIM / 128, NPAIR / 128, E_NUM), 256, 0, stream>>>(xb, w1t, b1, pair_token, eoff, counts, hbuf);
  gemm2_kernel<<<dim3(O_DIM / 128, NPAIR / 128, E_NUM), 256, 0, stream>>>(hbuf, w2t, b2, pair_token, pair_gate, eoff, counts, out);
}